// Round 8
// baseline (726.931 us; speedup 1.0000x reference)
//
#include <hip/hip_runtime.h>
#include <hip/hip_fp16.h>
#include <stdint.h>
#include <stddef.h>

typedef float f32x4 __attribute__((ext_vector_type(4)));
typedef int   i32x8 __attribute__((ext_vector_type(8)));

#define GLOBAL_AS __attribute__((address_space(1)))
#define LDS_AS    __attribute__((address_space(3)))

__device__ __forceinline__ void gload_lds16(const void* g, void* l) {
    __builtin_amdgcn_global_load_lds((const GLOBAL_AS void*)g,
                                     (LDS_AS void*)l, 16, 0, 0);
}

// ---------------- fused amax (x -> scal[0], w -> scal[1]) ----------------
__global__ void amax2_kernel(const float* __restrict__ x, size_t nx4,
                             const float* __restrict__ w, size_t nw4,
                             float* __restrict__ scal, int xblocks, int wblocks) {
    int b = blockIdx.x;
    const float4* p4; size_t n4; float* out; int nb; int bb;
    if (b < xblocks) { p4 = (const float4*)x; n4 = nx4; out = scal;     nb = xblocks; bb = b; }
    else             { p4 = (const float4*)w; n4 = nw4; out = scal + 1; nb = wblocks; bb = b - xblocks; }
    float m = 0.f;
    for (size_t i = (size_t)bb * blockDim.x + threadIdx.x; i < n4;
         i += (size_t)nb * blockDim.x) {
        float4 v = p4[i];
        m = fmaxf(m, fmaxf(fmaxf(fabsf(v.x), fabsf(v.y)),
                           fmaxf(fabsf(v.z), fabsf(v.w))));
    }
    #pragma unroll
    for (int off = 32; off > 0; off >>= 1)
        m = fmaxf(m, __shfl_down(m, off, 64));
    __shared__ float sm[4];
    int wid = threadIdx.x >> 6;
    if ((threadIdx.x & 63) == 0) sm[wid] = m;
    __syncthreads();
    if (threadIdx.x == 0) {
        m = fmaxf(fmaxf(sm[0], sm[1]), fmaxf(sm[2], sm[3]));
        atomicMax((unsigned int*)out, __float_as_uint(m));
    }
}

// ---------------- fused fp8 e4m3 quantization (16 elems/thread) ----------------
__global__ void quant2_kernel(const float* __restrict__ x, const float* __restrict__ w,
                              const float* __restrict__ scal,
                              uint32_t* __restrict__ qx, uint32_t* __restrict__ qw,
                              int xblocks) {
    int b = blockIdx.x;
    const float* src; uint32_t* dst; float sc; size_t i;
    if (b < xblocks) { src = x; dst = qx; sc = 448.f / fmaxf(scal[0], 1e-12f);
                       i = (size_t)b * blockDim.x + threadIdx.x; }
    else             { src = w; dst = qw; sc = 448.f / fmaxf(scal[1], 1e-12f);
                       i = (size_t)(b - xblocks) * blockDim.x + threadIdx.x; }
    const float4* s4 = (const float4*)src + i * 4;
    uint32_t r[4];
    #pragma unroll
    for (int j = 0; j < 4; ++j) {
        float4 v = s4[j];
        uint32_t u = __builtin_amdgcn_cvt_pk_fp8_f32(v.x * sc, v.y * sc, 0u, false);
        u = __builtin_amdgcn_cvt_pk_fp8_f32(v.z * sc, v.w * sc, u, true);
        r[j] = u;
    }
    uint4 out; out.x = r[0]; out.y = r[1]; out.z = r[2]; out.w = r[3];
    *(uint4*)(dst + i * 4) = out;
}

// ---- MX-fp8 256x256 8-phase GEMM: C = A[M][K] * B[N][K]^T ----
// vs r7: in-place ds_read into named fragment halves (no int4 temp block),
// <=1 stage unit per phase. Arch-reg demand ~70 of the 128 left by acc=128.
#define BM 256
#define BN 256
#define BKB 128   // K-bytes per tile

__global__ __launch_bounds__(512, 2) void gemm_mxfp8_8p4(
    const uint8_t* __restrict__ Aq,   // [M][K] fp8
    const uint8_t* __restrict__ Bq,   // [N][K] fp8
    const float* __restrict__ scal,
    const float* __restrict__ bias,   // [N] f32 (fp16-exact values)
    float* __restrict__ C,            // [M][N] f32 (fp16-rounded values)
    int M, int N, int K)
{
    // [buf][op A=0/B=1][half][128 rows * 128 B] = 128 KiB
    __shared__ __align__(16) uint8_t lds[2][2][2][128 * 128];

    const int tid  = threadIdx.x;
    const int wid  = tid >> 6;
    const int lane = tid & 63;
    const int wm = wid >> 2;           // 0..1: row half (128 rows)
    const int wn = wid & 3;            // 0..3: col quarter (64 cols)
    const int r16 = lane & 15, hi = lane >> 4;

    // XCD-aware bijective swizzle (nwg = 2048, %8 == 0)
    const int cpx = gridDim.x >> 3;
    const int sbid = (blockIdx.x & 7) * cpx + (blockIdx.x >> 3);
    const int nbn = N / BN;            // 32
    const int bn = sbid & (nbn - 1);
    const int bm = sbid / nbn;

    const uint8_t* Abase = Aq + (size_t)bm * BM * K;
    const uint8_t* Bbase = Bq + (size_t)bn * BN * K;

    // staging: one unit = 128 rows x 128 B (16 KB), 2 x 16B per thread
    const int srow = tid >> 3;                                   // 0..63
    const uint32_t soff = (uint32_t)srow * (uint32_t)K +
                          (uint32_t)(((tid & 7) ^ (srow & 7)) << 4);

    // fragment-read swizzled chunk offsets (row & 7 == r16 & 7)
    const int swz = r16 & 7;
    const int u0 = ((hi * 2)     ^ swz) << 4;
    const int u1 = ((hi * 2 + 1) ^ swz) << 4;

#define STAGE_A(bufi, h, s)                                                       \
  { const uint8_t* g_ = Abase + (uint32_t)((h) * 128 * K + (s) * BKB) + soff;     \
    uint8_t* l_ = &lds[bufi][0][h][tid * 16];                                     \
    gload_lds16(g_, l_);                                                          \
    gload_lds16(g_ + (uint32_t)(64 * K), l_ + 8192); }

#define STAGE_B(bufi, h, s)                                                       \
  { const uint8_t* g_ = Bbase + (uint32_t)((h) * 128 * K + (s) * BKB) + soff;     \
    uint8_t* l_ = &lds[bufi][1][h][tid * 16];                                     \
    gload_lds16(g_, l_);                                                          \
    gload_lds16(g_ + (uint32_t)(64 * K), l_ + 8192); }

// in-place fragment load: two ds_read_b128 straight into dst's halves
#define LDFRAG(dst, pbase, row)                                                   \
  { const uint8_t* p_ = (pbase) + (row) * 128;                                    \
    ((int4*)&(dst))[0] = *(const int4*)(p_ + u0);                                 \
    ((int4*)&(dst))[1] = *(const int4*)(p_ + u1); }

// a0,a1 <- m-quarter q (rows q*32..q*32+31) of this wave's 128-row half
#define LDA(bufc, q)                                                              \
  { const uint8_t* pa_ = &lds[bufc][0][wm][0];                                    \
    LDFRAG(a0, pa_, (q) * 32 + r16);                                              \
    LDFRAG(a1, pa_, (q) * 32 + 16 + r16); }

// b0..b3 <- this wave's full 64-col slice (held across the 4 phases of a tile)
#define LDB(bufc)                                                                 \
  { const uint8_t* pb_ = &lds[bufc][1][wn >> 1][(wn & 1) * 64 * 128];             \
    LDFRAG(b0, pb_, r16);                                                         \
    LDFRAG(b1, pb_, 16 + r16);                                                    \
    LDFRAG(b2, pb_, 32 + r16);                                                    \
    LDFRAG(b3, pb_, 48 + r16); }

#define MM1(am, bn_, q, mi_, nj_)                                                 \
  acc[(q) * 2 + (mi_)][nj_] = __builtin_amdgcn_mfma_scale_f32_16x16x128_f8f6f4(   \
      am, bn_, acc[(q) * 2 + (mi_)][nj_], 0, 0, 0, 0x7F7F7F7F, 0, 0x7F7F7F7F);

#define MMA(q)                                                                    \
  __builtin_amdgcn_s_setprio(1);                                                  \
  MM1(a0, b0, q, 0, 0) MM1(a0, b1, q, 0, 1) MM1(a0, b2, q, 0, 2)                  \
  MM1(a0, b3, q, 0, 3) MM1(a1, b0, q, 1, 0) MM1(a1, b1, q, 1, 1)                  \
  MM1(a1, b2, q, 1, 2) MM1(a1, b3, q, 1, 3)                                       \
  __builtin_amdgcn_s_setprio(0);

#define PH_BEGIN() do { asm volatile("" ::: "memory");                            \
    __builtin_amdgcn_s_barrier(); } while (0)
#define PH_END()   do { asm volatile("" ::: "memory");                            \
    __builtin_amdgcn_s_barrier(); } while (0)
#define PH_END_VM(n) do { asm volatile("s_waitcnt vmcnt(" #n ")" ::: "memory");   \
    __builtin_amdgcn_s_barrier(); } while (0)

    f32x4 acc[8][4] = {};
    i32x8 a0, a1, b0, b1, b2, b3;

    // ---- prologue: t0 {B,A} -> buf0 ; t1 {B} -> buf1 (6 units) ----
    STAGE_B(0, 0, 0);
    STAGE_B(0, 1, 0);
    STAGE_A(0, 0, 0);
    STAGE_A(0, 1, 0);
    STAGE_B(1, 0, 1);
    STAGE_B(1, 1, 1);
    asm volatile("s_waitcnt vmcnt(4)" ::: "memory");   // t0 resident; B(t1) in flight
    __builtin_amdgcn_s_barrier();

    // ITER(t): tile t (buf0, P1-P4) then t+1 (buf1, P5-P8). One stage unit/phase:
    //   P1: A(t+1)h0->buf1   P2: A(t+1)h1->buf1
    //   P3: B(t+2)h0->buf0   P4: B(t+2)h1->buf0
    //   P5: A(t+2)h0->buf0   P6: A(t+2)h1->buf0
    //   P7: B(t+3)h0->buf1   P8: B(t+3)h1->buf1
    // vmcnt(4)@P4 completes through A(t+1); @P8 through {B,A}(t+2).
    // Every overwrite is >=1 barrier after the last read of the old data.
#define ITER(t, LAST) do {                                                        \
    /* P1 */                                                                      \
    LDB(0); LDA(0, 0); STAGE_A(1, 0, (t) + 1);                                    \
    PH_BEGIN(); MMA(0); PH_END();                                                 \
    /* P2 */                                                                      \
    LDA(0, 1); STAGE_A(1, 1, (t) + 1);                                            \
    PH_BEGIN(); MMA(1); PH_END();                                                 \
    /* P3 */                                                                      \
    LDA(0, 2); if (!(LAST)) STAGE_B(0, 0, (t) + 2);                               \
    PH_BEGIN(); MMA(2); PH_END();                                                 \
    /* P4 */                                                                      \
    LDA(0, 3); if (!(LAST)) STAGE_B(0, 1, (t) + 2);                               \
    PH_BEGIN(); MMA(3);                                                           \
    if (LAST) { PH_END_VM(0); } else { PH_END_VM(4); }                            \
    /* P5 */                                                                      \
    LDB(1); LDA(1, 0); if (!(LAST)) STAGE_A(0, 0, (t) + 2);                       \
    PH_BEGIN(); MMA(0); PH_END();                                                 \
    /* P6 */                                                                      \
    LDA(1, 1); if (!(LAST)) STAGE_A(0, 1, (t) + 2);                               \
    PH_BEGIN(); MMA(1); PH_END();                                                 \
    /* P7 */                                                                      \
    LDA(1, 2); if (!(LAST)) STAGE_B(1, 0, (t) + 3);                               \
    PH_BEGIN(); MMA(2); PH_END();                                                 \
    /* P8 */                                                                      \
    LDA(1, 3); if (!(LAST)) STAGE_B(1, 1, (t) + 3);                               \
    PH_BEGIN(); MMA(3);                                                           \
    if (LAST) { PH_END(); } else { PH_END_VM(4); }                                \
  } while (0)

    const int NTILES = K / BKB;   // 16
    for (int t = 0; t < NTILES - 2; t += 2) { ITER(t, false); }
    ITER(NTILES - 2, true);

    // ---- epilogue: scale, fp16-round, fp16 bias add, widen to f32 ----
    const float sx = 448.f / fmaxf(scal[0], 1e-12f);
    const float sw = 448.f / fmaxf(scal[1], 1e-12f);
    const float inv = (1.f / sx) * (1.f / sw);

    #pragma unroll
    for (int mi = 0; mi < 8; ++mi) {
        #pragma unroll
        for (int nj = 0; nj < 4; ++nj) {
            int col = bn * BN + wn * 64 + nj * 16 + r16;
            __half hb = __float2half(bias[col]);
            #pragma unroll
            for (int r = 0; r < 4; ++r) {
                int row = bm * BM + wm * 128 + mi * 16 + hi * 4 + r;
                float v = acc[mi][nj][r] * inv;
                __half h = __hadd(__float2half(v), hb);
                C[(size_t)row * N + col] = __half2float(h);
            }
        }
    }
}

extern "C" void kernel_launch(void* const* d_in, const int* in_sizes, int n_in,
                              void* d_out, int out_size, void* d_ws, size_t ws_size,
                              hipStream_t stream) {
    const float* x    = (const float*)d_in[0];
    const float* w    = (const float*)d_in[1];
    const float* bias = (const float*)d_in[2];   // fp16 in reference -> f32 on device
    float* out = (float*)d_out;

    const int N = in_sizes[2];              // 8192
    const int K = in_sizes[1] / N;          // 2048
    const int M = in_sizes[0] / K;          // 16384

    uint8_t* ws = (uint8_t*)d_ws;
    float* scal = (float*)ws;               // [0]=amax_x, [1]=amax_w
    uint8_t* Aq = ws + 256;
    uint8_t* Bq = Aq + (size_t)M * K;

    hipMemsetAsync(scal, 0, 8, stream);

    const int axb = 2048, awb = 1024;
    amax2_kernel<<<axb + awb, 256, 0, stream>>>(x, (size_t)M * K / 4,
                                                w, (size_t)N * K / 4,
                                                scal, axb, awb);

    int qxb = (int)((size_t)M * K / 16 / 256);   // 8192
    int qwb = (int)((size_t)N * K / 16 / 256);   // 4096
    quant2_kernel<<<qxb + qwb, 256, 0, stream>>>(x, w, scal,
                                                 (uint32_t*)Aq, (uint32_t*)Bq, qxb);

    dim3 grid((N / BN) * (M / BM));   // 2048
    gemm_mxfp8_8p4<<<grid, 512, 0, stream>>>(Aq, Bq, scal, bias, out, M, N, K);
}

// Round 10
// 490.636 us; speedup vs baseline: 1.4816x; 1.4816x over previous
//
#include <hip/hip_runtime.h>
#include <hip/hip_fp16.h>
#include <stdint.h>
#include <stddef.h>

typedef float f32x4 __attribute__((ext_vector_type(4)));
typedef int   i32x8 __attribute__((ext_vector_type(8)));

#define GLOBAL_AS __attribute__((address_space(1)))
#define LDS_AS    __attribute__((address_space(3)))

__device__ __forceinline__ void gload_lds16(const void* g, void* l) {
    __builtin_amdgcn_global_load_lds((const GLOBAL_AS void*)g,
                                     (LDS_AS void*)l, 16, 0, 0);
}

// ---------------- fused amax (x -> scal[0], w -> scal[1]) ----------------
__global__ void amax2_kernel(const float* __restrict__ x, size_t nx4,
                             const float* __restrict__ w, size_t nw4,
                             float* __restrict__ scal, int xblocks, int wblocks) {
    int b = blockIdx.x;
    const float4* p4; size_t n4; float* out; int nb; int bb;
    if (b < xblocks) { p4 = (const float4*)x; n4 = nx4; out = scal;     nb = xblocks; bb = b; }
    else             { p4 = (const float4*)w; n4 = nw4; out = scal + 1; nb = wblocks; bb = b - xblocks; }
    float m = 0.f;
    for (size_t i = (size_t)bb * blockDim.x + threadIdx.x; i < n4;
         i += (size_t)nb * blockDim.x) {
        float4 v = p4[i];
        m = fmaxf(m, fmaxf(fmaxf(fabsf(v.x), fabsf(v.y)),
                           fmaxf(fabsf(v.z), fabsf(v.w))));
    }
    #pragma unroll
    for (int off = 32; off > 0; off >>= 1)
        m = fmaxf(m, __shfl_down(m, off, 64));
    __shared__ float sm[4];
    int wid = threadIdx.x >> 6;
    if ((threadIdx.x & 63) == 0) sm[wid] = m;
    __syncthreads();
    if (threadIdx.x == 0) {
        m = fmaxf(fmaxf(sm[0], sm[1]), fmaxf(sm[2], sm[3]));
        atomicMax((unsigned int*)out, __float_as_uint(m));
    }
}

// ---------------- fused fp8 e4m3 quantization (16 elems/thread) ----------------
__global__ void quant2_kernel(const float* __restrict__ x, const float* __restrict__ w,
                              const float* __restrict__ scal,
                              uint32_t* __restrict__ qx, uint32_t* __restrict__ qw,
                              int xblocks) {
    int b = blockIdx.x;
    const float* src; uint32_t* dst; float sc; size_t i;
    if (b < xblocks) { src = x; dst = qx; sc = 448.f / fmaxf(scal[0], 1e-12f);
                       i = (size_t)b * blockDim.x + threadIdx.x; }
    else             { src = w; dst = qw; sc = 448.f / fmaxf(scal[1], 1e-12f);
                       i = (size_t)(b - xblocks) * blockDim.x + threadIdx.x; }
    const float4* s4 = (const float4*)src + i * 4;
    uint32_t r[4];
    #pragma unroll
    for (int j = 0; j < 4; ++j) {
        float4 v = s4[j];
        uint32_t u = __builtin_amdgcn_cvt_pk_fp8_f32(v.x * sc, v.y * sc, 0u, false);
        u = __builtin_amdgcn_cvt_pk_fp8_f32(v.z * sc, v.w * sc, u, true);
        r[j] = u;
    }
    uint4 out; out.x = r[0]; out.y = r[1]; out.z = r[2]; out.w = r[3];
    *(uint4*)(dst + i * 4) = out;
}

// ------- MX-fp8 GEMM (unit scales): C[M][N] = A[M][K] * B[N][K]^T -------
// EXACT round-3 structure (351 us, VGPR 80, no spill) + XCD-chunked grid:
// each XCD owns a 16-bm x 64-bn chunk, bm-fastest -> its 16 A-panels (4 MB)
// stay hot in the XCD L2; each B-panel shared by 16 consecutive blocks.
#define BM 128
#define BN 128
#define BKB 128

__global__ __launch_bounds__(256) void gemm_mxfp8_kernel(
    const uint8_t* __restrict__ Aq,   // [M][K] fp8
    const uint8_t* __restrict__ Bq,   // [N][K] fp8
    const float* __restrict__ scal,   // {amax_x, amax_w}
    const float* __restrict__ bias,   // [N] f32 holding fp16-exact values
    float* __restrict__ C,            // [M][N] f32 (fp16-rounded values)
    int M, int N, int K)
{
    __shared__ __align__(16) uint8_t As[BM * BKB];   // 16 KB
    __shared__ __align__(16) uint8_t Bs[BN * BKB];   // 16 KB

    const int tid  = threadIdx.x;
    const int wid  = tid >> 6;
    const int lane = tid & 63;
    const int wm = wid >> 1, wn = wid & 1;   // 2x2 waves, 64x64 each
    const int r16 = lane & 15, hi = lane >> 4;

    // XCD-chunked mapping: 8192 blocks = 8 XCD x (16 bm x 64 bn), bm fastest
    const int bid  = blockIdx.x;
    const int xcd  = bid & 7;
    const int loc  = bid >> 3;                 // 0..1023 within XCD
    const int bm   = xcd * 16 + (loc & 15);    // 0..127
    const int bn   = loc >> 4;                 // 0..63

    // ---- staging addresses (pre-swizzled global source) ----
    const int srow  = wid * 8 + (lane >> 3);
    const int schunk = ((lane & 7) ^ (lane >> 3)) << 4;
    const uint8_t* Abase = Aq + (size_t)(bm * BM + srow) * K + schunk;
    const uint8_t* Bbase = Bq + (size_t)(bn * BN + srow) * K + schunk;

    // ---- fragment-read swizzle: row&7 == r16&7 for all mi ----
    const int swz = r16 & 7;
    const int u0 = ((hi * 2)     ^ swz) << 4;
    const int u1 = ((hi * 2 + 1) ^ swz) << 4;

    f32x4 acc[4][4] = {};

    for (int k0 = 0; k0 < K; k0 += BKB) {
        #pragma unroll
        for (int rho = 0; rho < 4; ++rho) {
            gload_lds16(Abase + (size_t)rho * 32 * K + k0,
                        As + rho * 4096 + wid * 1024);
            gload_lds16(Bbase + (size_t)rho * 32 * K + k0,
                        Bs + rho * 4096 + wid * 1024);
        }
        __syncthreads();

        i32x8 a[4], b[4];
        #pragma unroll
        for (int mi = 0; mi < 4; ++mi) {
            const uint8_t* pa = As + (wm * 64 + mi * 16 + r16) * BKB;
            int4 qa0 = *(const int4*)(pa + u0);
            int4 qa1 = *(const int4*)(pa + u1);
            a[mi] = (i32x8){qa0.x, qa0.y, qa0.z, qa0.w,
                            qa1.x, qa1.y, qa1.z, qa1.w};
            const uint8_t* pb = Bs + (wn * 64 + mi * 16 + r16) * BKB;
            int4 qb0 = *(const int4*)(pb + u0);
            int4 qb1 = *(const int4*)(pb + u1);
            b[mi] = (i32x8){qb0.x, qb0.y, qb0.z, qb0.w,
                            qb1.x, qb1.y, qb1.z, qb1.w};
        }

        #pragma unroll
        for (int mi = 0; mi < 4; ++mi)
            #pragma unroll
            for (int nj = 0; nj < 4; ++nj)
                acc[mi][nj] = __builtin_amdgcn_mfma_scale_f32_16x16x128_f8f6f4(
                    a[mi], b[nj], acc[mi][nj],
                    0, 0, 0, 0x7F7F7F7F, 0, 0x7F7F7F7F);
        __syncthreads();
    }

    // epilogue: scale, fp16-round, fp16 bias add, widen to f32
    const float sx = 448.f / fmaxf(scal[0], 1e-12f);
    const float sw = 448.f / fmaxf(scal[1], 1e-12f);
    const float inv = (1.f / sx) * (1.f / sw);

    #pragma unroll
    for (int mi = 0; mi < 4; ++mi) {
        #pragma unroll
        for (int nj = 0; nj < 4; ++nj) {
            int col = bn * BN + wn * 64 + nj * 16 + r16;
            __half hb = __float2half(bias[col]);
            #pragma unroll
            for (int r = 0; r < 4; ++r) {
                int row = bm * BM + wm * 64 + mi * 16 + hi * 4 + r;
                float v = acc[mi][nj][r] * inv;
                __half h = __hadd(__float2half(v), hb);
                C[(size_t)row * N + col] = __half2float(h);
            }
        }
    }
}

extern "C" void kernel_launch(void* const* d_in, const int* in_sizes, int n_in,
                              void* d_out, int out_size, void* d_ws, size_t ws_size,
                              hipStream_t stream) {
    const float* x    = (const float*)d_in[0];
    const float* w    = (const float*)d_in[1];
    const float* bias = (const float*)d_in[2];   // fp16 in reference -> f32 on device
    float* out = (float*)d_out;

    const int N = in_sizes[2];              // 8192
    const int K = in_sizes[1] / N;          // 2048
    const int M = in_sizes[0] / K;          // 16384

    uint8_t* ws = (uint8_t*)d_ws;
    float* scal = (float*)ws;               // [0]=amax_x, [1]=amax_w
    uint8_t* Aq = ws + 256;
    uint8_t* Bq = Aq + (size_t)M * K;

    hipMemsetAsync(scal, 0, 8, stream);

    const int axb = 2048, awb = 1024;
    amax2_kernel<<<axb + awb, 256, 0, stream>>>(x, (size_t)M * K / 4,
                                                w, (size_t)N * K / 4,
                                                scal, axb, awb);

    int qxb = (int)((size_t)M * K / 16 / 256);   // 8192
    int qwb = (int)((size_t)N * K / 16 / 256);   // 4096
    quant2_kernel<<<qxb + qwb, 256, 0, stream>>>(x, w, scal,
                                                 (uint32_t*)Aq, (uint32_t*)Bq, qxb);

    dim3 grid((N / BN) * (M / BM));   // 8192
    gemm_mxfp8_kernel<<<grid, 256, 0, stream>>>(Aq, Bq, scal, bias, out, M, N, K);
}

// Round 13
// 444.750 us; speedup vs baseline: 1.6345x; 1.1032x over previous
//
#include <hip/hip_runtime.h>
#include <hip/hip_fp16.h>
#include <stdint.h>
#include <stddef.h>

typedef float f32x4 __attribute__((ext_vector_type(4)));
typedef int   i32x8 __attribute__((ext_vector_type(8)));

#define GLOBAL_AS __attribute__((address_space(1)))
#define LDS_AS    __attribute__((address_space(3)))

__device__ __forceinline__ void gload_lds16(const void* g, void* l) {
    __builtin_amdgcn_global_load_lds((const GLOBAL_AS void*)g,
                                     (LDS_AS void*)l, 16, 0, 0);
}

// ---------------- fused amax (x -> scal[0], w -> scal[1]) ----------------
__global__ void amax2_kernel(const float* __restrict__ x, size_t nx4,
                             const float* __restrict__ w, size_t nw4,
                             float* __restrict__ scal, int xblocks, int wblocks) {
    int b = blockIdx.x;
    const float4* p4; size_t n4; float* out; int nb; int bb;
    if (b < xblocks) { p4 = (const float4*)x; n4 = nx4; out = scal;     nb = xblocks; bb = b; }
    else             { p4 = (const float4*)w; n4 = nw4; out = scal + 1; nb = wblocks; bb = b - xblocks; }
    float m = 0.f;
    for (size_t i = (size_t)bb * blockDim.x + threadIdx.x; i < n4;
         i += (size_t)nb * blockDim.x) {
        float4 v = p4[i];
        m = fmaxf(m, fmaxf(fmaxf(fabsf(v.x), fabsf(v.y)),
                           fmaxf(fabsf(v.z), fabsf(v.w))));
    }
    #pragma unroll
    for (int off = 32; off > 0; off >>= 1)
        m = fmaxf(m, __shfl_down(m, off, 64));
    __shared__ float sm[4];
    int wid = threadIdx.x >> 6;
    if ((threadIdx.x & 63) == 0) sm[wid] = m;
    __syncthreads();
    if (threadIdx.x == 0) {
        m = fmaxf(fmaxf(sm[0], sm[1]), fmaxf(sm[2], sm[3]));
        atomicMax((unsigned int*)out, __float_as_uint(m));
    }
}

// ---------------- fused fp8 e4m3 quantization (16 elems/thread) ----------------
__global__ void quant2_kernel(const float* __restrict__ x, const float* __restrict__ w,
                              const float* __restrict__ scal,
                              uint32_t* __restrict__ qx, uint32_t* __restrict__ qw,
                              int xblocks) {
    int b = blockIdx.x;
    const float* src; uint32_t* dst; float sc; size_t i;
    if (b < xblocks) { src = x; dst = qx; sc = 448.f / fmaxf(scal[0], 1e-12f);
                       i = (size_t)b * blockDim.x + threadIdx.x; }
    else             { src = w; dst = qw; sc = 448.f / fmaxf(scal[1], 1e-12f);
                       i = (size_t)(b - xblocks) * blockDim.x + threadIdx.x; }
    const float4* s4 = (const float4*)src + i * 4;
    uint32_t r[4];
    #pragma unroll
    for (int j = 0; j < 4; ++j) {
        float4 v = s4[j];
        uint32_t u = __builtin_amdgcn_cvt_pk_fp8_f32(v.x * sc, v.y * sc, 0u, false);
        u = __builtin_amdgcn_cvt_pk_fp8_f32(v.z * sc, v.w * sc, u, true);
        r[j] = u;
    }
    uint4 out; out.x = r[0]; out.y = r[1]; out.z = r[2]; out.w = r[3];
    *(uint4*)(dst + i * 4) = out;
}

// ------- MX-fp8 GEMM (unit scales): C[M][N] = A[M][K] * B[N][K]^T -------
// EXACT round-3 structure and grid (351 us, VGPR 80, no spill, MfmaUtil 34%).
// r10's XCD-chunked grid regressed (-7%: concurrent 16 A-panels + B + C-write
// stream thrash the 4MB XCD L2); default bn-fast round-robin is best measured.
#define BM 128
#define BN 128
#define BKB 128

__global__ __launch_bounds__(256) void gemm_mxfp8_kernel(
    const uint8_t* __restrict__ Aq,   // [M][K] fp8
    const uint8_t* __restrict__ Bq,   // [N][K] fp8
    const float* __restrict__ scal,   // {amax_x, amax_w}
    const float* __restrict__ bias,   // [N] f32 holding fp16-exact values
    float* __restrict__ C,            // [M][N] f32 (fp16-rounded values)
    int M, int N, int K)
{
    __shared__ __align__(16) uint8_t As[BM * BKB];   // 16 KB
    __shared__ __align__(16) uint8_t Bs[BN * BKB];   // 16 KB

    const int tid  = threadIdx.x;
    const int wid  = tid >> 6;
    const int lane = tid & 63;
    const int wm = wid >> 1, wn = wid & 1;   // 2x2 waves, 64x64 each
    const int bn = blockIdx.x, bm = blockIdx.y;
    const int r16 = lane & 15, hi = lane >> 4;

    // ---- staging addresses (pre-swizzled global source) ----
    const int srow  = wid * 8 + (lane >> 3);
    const int schunk = ((lane & 7) ^ (lane >> 3)) << 4;
    const uint8_t* Abase = Aq + (size_t)(bm * BM + srow) * K + schunk;
    const uint8_t* Bbase = Bq + (size_t)(bn * BN + srow) * K + schunk;

    // ---- fragment-read swizzle: row&7 == r16&7 for all mi ----
    const int swz = r16 & 7;
    const int u0 = ((hi * 2)     ^ swz) << 4;
    const int u1 = ((hi * 2 + 1) ^ swz) << 4;

    f32x4 acc[4][4] = {};

    for (int k0 = 0; k0 < K; k0 += BKB) {
        #pragma unroll
        for (int rho = 0; rho < 4; ++rho) {
            gload_lds16(Abase + (size_t)rho * 32 * K + k0,
                        As + rho * 4096 + wid * 1024);
            gload_lds16(Bbase + (size_t)rho * 32 * K + k0,
                        Bs + rho * 4096 + wid * 1024);
        }
        __syncthreads();

        i32x8 a[4], b[4];
        #pragma unroll
        for (int mi = 0; mi < 4; ++mi) {
            const uint8_t* pa = As + (wm * 64 + mi * 16 + r16) * BKB;
            int4 qa0 = *(const int4*)(pa + u0);
            int4 qa1 = *(const int4*)(pa + u1);
            a[mi] = (i32x8){qa0.x, qa0.y, qa0.z, qa0.w,
                            qa1.x, qa1.y, qa1.z, qa1.w};
            const uint8_t* pb = Bs + (wn * 64 + mi * 16 + r16) * BKB;
            int4 qb0 = *(const int4*)(pb + u0);
            int4 qb1 = *(const int4*)(pb + u1);
            b[mi] = (i32x8){qb0.x, qb0.y, qb0.z, qb0.w,
                            qb1.x, qb1.y, qb1.z, qb1.w};
        }

        #pragma unroll
        for (int mi = 0; mi < 4; ++mi)
            #pragma unroll
            for (int nj = 0; nj < 4; ++nj)
                acc[mi][nj] = __builtin_amdgcn_mfma_scale_f32_16x16x128_f8f6f4(
                    a[mi], b[nj], acc[mi][nj],
                    0, 0, 0, 0x7F7F7F7F, 0, 0x7F7F7F7F);
        __syncthreads();
    }

    // epilogue: scale, fp16-round, fp16 bias add, widen to f32
    const float sx = 448.f / fmaxf(scal[0], 1e-12f);
    const float sw = 448.f / fmaxf(scal[1], 1e-12f);
    const float inv = (1.f / sx) * (1.f / sw);

    #pragma unroll
    for (int mi = 0; mi < 4; ++mi) {
        #pragma unroll
        for (int nj = 0; nj < 4; ++nj) {
            int col = bn * BN + wn * 64 + nj * 16 + r16;
            __half hb = __float2half(bias[col]);
            #pragma unroll
            for (int r = 0; r < 4; ++r) {
                int row = bm * BM + wm * 64 + mi * 16 + hi * 4 + r;
                float v = acc[mi][nj][r] * inv;
                __half h = __hadd(__float2half(v), hb);
                C[(size_t)row * N + col] = __half2float(h);
            }
        }
    }
}

extern "C" void kernel_launch(void* const* d_in, const int* in_sizes, int n_in,
                              void* d_out, int out_size, void* d_ws, size_t ws_size,
                              hipStream_t stream) {
    const float* x    = (const float*)d_in[0];
    const float* w    = (const float*)d_in[1];
    const float* bias = (const float*)d_in[2];   // fp16 in reference -> f32 on device
    float* out = (float*)d_out;

    const int N = in_sizes[2];              // 8192
    const int K = in_sizes[1] / N;          // 2048
    const int M = in_sizes[0] / K;          // 16384

    uint8_t* ws = (uint8_t*)d_ws;
    float* scal = (float*)ws;               // [0]=amax_x, [1]=amax_w
    uint8_t* Aq = ws + 256;
    uint8_t* Bq = Aq + (size_t)M * K;

    hipMemsetAsync(scal, 0, 8, stream);

    const int axb = 2048, awb = 1024;
    amax2_kernel<<<axb + awb, 256, 0, stream>>>(x, (size_t)M * K / 4,
                                                w, (size_t)N * K / 4,
                                                scal, axb, awb);

    int qxb = (int)((size_t)M * K / 16 / 256);   // 8192
    int qwb = (int)((size_t)N * K / 16 / 256);   // 4096
    quant2_kernel<<<qxb + qwb, 256, 0, stream>>>(x, w, scal,
                                                 (uint32_t*)Aq, (uint32_t*)Bq, qxb);

    dim3 grid(N / BN, M / BM);   // 64 x 128, bn fast (r3-exact)
    gemm_mxfp8_kernel<<<grid, 256, 0, stream>>>(Aq, Bq, scal, bias, out, M, N, K);
}